// Round 2
// baseline (440.930 us; speedup 1.0000x reference)
//
#include <hip/hip_runtime.h>
#include <hip/hip_bf16.h>
#include <math.h>

#define B_SZ   1024
#define CDIM   768
#define POOL   100
#define LP     8
#define COSEPS 1e-6f

// ---------------- Kernel 1: prep (softmax rows of A, W1/W2/k_norm) ----------
__global__ void prep_kernel(const float* __restrict__ A, const float* __restrict__ K,
                            float* __restrict__ W1, float* __restrict__ W2,
                            float* __restrict__ knorm) {
    const int k = blockIdx.x;       // 0..99
    const int t = threadIdx.x;      // 0..255
    __shared__ float red[256];

    const float* Ar = A + (size_t)k * CDIM;
    const float* Kr = K + (size_t)k * CDIM;

    // row max of A
    float m = -INFINITY;
    for (int d = t; d < CDIM; d += 256) m = fmaxf(m, Ar[d]);
    red[t] = m; __syncthreads();
    for (int s = 128; s > 0; s >>= 1) { if (t < s) red[t] = fmaxf(red[t], red[t + s]); __syncthreads(); }
    m = red[0]; __syncthreads();

    // sum of exp
    float sum = 0.f;
    for (int d = t; d < CDIM; d += 256) sum += expf(Ar[d] - m);
    red[t] = sum; __syncthreads();
    for (int s = 128; s > 0; s >>= 1) { if (t < s) red[t] += red[t + s]; __syncthreads(); }
    sum = red[0]; __syncthreads();
    const float inv = 1.0f / sum;

    // K row squared-norm
    float ksq = 0.f;
    for (int d = t; d < CDIM; d += 256) { float kv = Kr[d]; ksq += kv * kv; }
    red[t] = ksq; __syncthreads();
    for (int s = 128; s > 0; s >>= 1) { if (t < s) red[t] += red[t + s]; __syncthreads(); }
    if (t == 0) knorm[k] = fmaxf(sqrtf(red[0]), COSEPS);

    // W1 = A_sm * K, W2 = A_sm^2
    for (int d = t; d < CDIM; d += 256) {
        float a_sm = expf(Ar[d] - m) * inv;
        W1[(size_t)k * CDIM + d] = a_sm * Kr[d];
        W2[(size_t)k * CDIM + d] = a_sm * a_sm;
    }
}

// ---------------- Kernel 2: aq[b][k] -----------------------------------------
__global__ void aq_kernel(const float* __restrict__ xq,
                          const float* __restrict__ W1, const float* __restrict__ W2,
                          const float* __restrict__ knorm, float* __restrict__ aq) {
    const int b = blockIdx.x;     // 0..1023
    const int t = threadIdx.x;    // 0..255 (4 waves of 64)
    __shared__ float xs[CDIM];
    __shared__ float x2s[CDIM];

    for (int d = t; d < CDIM; d += 256) {
        float v = xq[(size_t)b * CDIM + d];
        xs[d] = v; x2s[d] = v * v;
    }
    __syncthreads();

    const int wave = t >> 6, lane = t & 63;
    for (int k = wave; k < POOL; k += 4) {
        const float* w1 = W1 + (size_t)k * CDIM;
        const float* w2 = W2 + (size_t)k * CDIM;
        float s1 = 0.f, s2 = 0.f;
        #pragma unroll
        for (int i = 0; i < CDIM / 64; ++i) {
            int d = lane + i * 64;
            s1 += xs[d] * w1[d];
            s2 += x2s[d] * w2[d];
        }
        // wave-64 reduction
        for (int off = 32; off > 0; off >>= 1) {
            s1 += __shfl_down(s1, off);
            s2 += __shfl_down(s2, off);
        }
        if (lane == 0) {
            float an = fmaxf(sqrtf(s2), COSEPS);
            float v  = s1 / (an * knorm[k]);
            aq[(size_t)b * POOL + k] = (v + 1.0f) * 0.5f;
        }
    }
}

// ---------------- Kernel 3: P_ = aq x p, write Ek/Ev --------------------------
// grid = 8 (l) * 128 (groups of 8 b), block = 256
__global__ void p_kernel(const float* __restrict__ aq, const float* __restrict__ p,
                         float* __restrict__ out) {
    const int l  = blockIdx.x & 7;
    const int bg = blockIdx.x >> 3;   // 0..127
    const int t  = threadIdx.x;
    __shared__ float a_s[POOL * 8];   // [k][bb]

    for (int i = t; i < POOL * 8; i += 256) {
        int bb = i & 7, k = i >> 3;
        a_s[i] = aq[(size_t)(bg * 8 + bb) * POOL + k];
    }
    __syncthreads();

    const float* pl = p + (size_t)l * POOL * CDIM + t;
    float acc[8][3];
    #pragma unroll
    for (int bb = 0; bb < 8; ++bb)
        #pragma unroll
        for (int j = 0; j < 3; ++j) acc[bb][j] = 0.f;

    for (int k = 0; k < POOL; ++k) {
        float p0 = pl[(size_t)k * CDIM];
        float p1 = pl[(size_t)k * CDIM + 256];
        float p2 = pl[(size_t)k * CDIM + 512];
        #pragma unroll
        for (int bb = 0; bb < 8; ++bb) {
            float a = a_s[k * 8 + bb];
            acc[bb][0] += a * p0;
            acc[bb][1] += a * p1;
            acc[bb][2] += a * p2;
        }
    }

    const size_t EK_SZ = (size_t)B_SZ * (LP / 2) * CDIM;   // 1024*4*768
    #pragma unroll
    for (int bb = 0; bb < 8; ++bb) {
        int b = bg * 8 + bb;
        float* dst = (l < 4)
            ? out + (size_t)b * (4 * CDIM) + (size_t)l * CDIM
            : out + EK_SZ + (size_t)b * (4 * CDIM) + (size_t)(l - 4) * CDIM;
        dst[t]       = acc[bb][0];
        dst[t + 256] = acc[bb][1];
        dst[t + 512] = acc[bb][2];
    }
}

// ---------------- Kernel 4: float4 grid-stride copy (x_block passthrough) ----
__global__ void copy_kernel(const float4* __restrict__ src, float4* __restrict__ dst,
                            int n4) {
    int i = blockIdx.x * blockDim.x + threadIdx.x;
    int stride = gridDim.x * blockDim.x;
    for (; i < n4; i += stride) dst[i] = src[i];
}

extern "C" void kernel_launch(void* const* d_in, const int* in_sizes, int n_in,
                              void* d_out, int out_size, void* d_ws, size_t ws_size,
                              hipStream_t stream) {
    const float* x_querry = (const float*)d_in[0];
    const float* x_block  = (const float*)d_in[1];
    const float* K        = (const float*)d_in[2];
    const float* A        = (const float*)d_in[3];
    const float* p        = (const float*)d_in[4];
    float* out = (float*)d_out;

    // workspace layout (floats)
    float* W1    = (float*)d_ws;                 // 100*768
    float* W2    = W1 + POOL * CDIM;             // 100*768
    float* knorm = W2 + POOL * CDIM;             // 100 (pad 128)
    float* aq    = knorm + 128;                  // 1024*100

    prep_kernel<<<POOL, 256, 0, stream>>>(A, K, W1, W2, knorm);
    aq_kernel<<<B_SZ, 256, 0, stream>>>(x_querry, W1, W2, knorm, aq);
    p_kernel<<<8 * (B_SZ / 8), 256, 0, stream>>>(aq, p, out);

    // x_block pass-through via shader copy (SDMA blit was ~3 TB/s; shader
    // float4 copy hits ~6.3 TB/s per m13)
    const size_t EK_SZ = (size_t)B_SZ * (LP / 2) * CDIM;   // 1024*4*768
    const int n4 = in_sizes[1] / 4;                        // x_block float4 count
    copy_kernel<<<2048, 256, 0, stream>>>(
        (const float4*)x_block, (float4*)(out + 2 * EK_SZ), n4);
}

// Round 4
// 286.103 us; speedup vs baseline: 1.5412x; 1.5412x over previous
//
#include <hip/hip_runtime.h>
#include <math.h>

#define B_SZ   1024
#define CDIM   768
#define POOL   100
#define COSEPS 1e-6f
#define NTHR   256

// ---------------- K1: prep (blocks 0..99) + copy slice [0,C1) ---------------
__global__ __launch_bounds__(NTHR)
void k1_prep_copy(const float* __restrict__ A, const float* __restrict__ K,
                  float* __restrict__ W1, float* __restrict__ W2,
                  float* __restrict__ knorm,
                  const float4* __restrict__ src4, float4* __restrict__ dst4,
                  int C1) {
    const int blk = blockIdx.x, t = threadIdx.x;
    if (blk < POOL) {
        __shared__ float red[NTHR];
        const int k = blk;
        const float* Ar = A + (size_t)k * CDIM;
        const float* Kr = K + (size_t)k * CDIM;

        float m = -INFINITY;
        for (int d = t; d < CDIM; d += NTHR) m = fmaxf(m, Ar[d]);
        red[t] = m; __syncthreads();
        for (int s = 128; s > 0; s >>= 1) { if (t < s) red[t] = fmaxf(red[t], red[t + s]); __syncthreads(); }
        m = red[0]; __syncthreads();

        float sum = 0.f;
        for (int d = t; d < CDIM; d += NTHR) sum += expf(Ar[d] - m);
        red[t] = sum; __syncthreads();
        for (int s = 128; s > 0; s >>= 1) { if (t < s) red[t] += red[t + s]; __syncthreads(); }
        sum = red[0]; __syncthreads();
        const float inv = 1.0f / sum;

        float ksq = 0.f;
        for (int d = t; d < CDIM; d += NTHR) { float kv = Kr[d]; ksq += kv * kv; }
        red[t] = ksq; __syncthreads();
        for (int s = 128; s > 0; s >>= 1) { if (t < s) red[t] += red[t + s]; __syncthreads(); }
        if (t == 0) knorm[k] = fmaxf(sqrtf(red[0]), COSEPS);

        for (int d = t; d < CDIM; d += NTHR) {
            float a_sm = expf(Ar[d] - m) * inv;
            W1[(size_t)k * CDIM + d] = a_sm * Kr[d];
            W2[(size_t)k * CDIM + d] = a_sm * a_sm;
        }
    } else {
        const int cid = blk - POOL;                 // 0..1947
        const int stride = (2048 - POOL) * NTHR;
        #pragma unroll 4
        for (int i = cid * NTHR + t; i < C1; i += stride) dst4[i] = src4[i];
    }
}

// ---------------- K2: aq (1024 blocks) + copy slice [C1,C2) -----------------
__global__ __launch_bounds__(NTHR)
void k2_aq_copy(const float* __restrict__ xq,
                const float* __restrict__ W1, const float* __restrict__ W2,
                const float* __restrict__ knorm, float* __restrict__ aq,
                const float4* __restrict__ src4, float4* __restrict__ dst4,
                int C1, int C2) {
    const int blk = blockIdx.x, t = threadIdx.x;
    const int role = (blk >> 3) & 1;                // groups of 8 -> all XCDs both roles
    const int id   = ((blk >> 4) << 3) | (blk & 7); // 0..1023 per role

    if (role) {  // copy
        #pragma unroll 4
        for (int i = C1 + id * NTHR + t; i < C2; i += 1024 * NTHR) dst4[i] = src4[i];
        return;
    }

    __shared__ float xs[CDIM];
    __shared__ float x2s[CDIM];
    const int b = id;
    for (int d = t; d < CDIM; d += NTHR) {
        float v = xq[(size_t)b * CDIM + d];
        xs[d] = v; x2s[d] = v * v;
    }
    __syncthreads();

    const int wave = t >> 6, lane = t & 63;
    for (int k = wave; k < POOL; k += 4) {
        const float* w1 = W1 + (size_t)k * CDIM;
        const float* w2 = W2 + (size_t)k * CDIM;
        float s1 = 0.f, s2 = 0.f;
        #pragma unroll
        for (int i = 0; i < CDIM / 64; ++i) {
            int d = lane + i * 64;
            s1 += xs[d]  * w1[d];
            s2 += x2s[d] * w2[d];
        }
        for (int off = 32; off > 0; off >>= 1) {
            s1 += __shfl_down(s1, off);
            s2 += __shfl_down(s2, off);
        }
        if (lane == 0) {
            float an = fmaxf(sqrtf(s2), COSEPS);
            float v  = s1 / (an * knorm[k]);
            aq[(size_t)b * POOL + k] = (v + 1.0f) * 0.5f;
        }
    }
}

// ---------------- K3: p-contraction (1024 blocks) + copy [C2,n4) ------------
__global__ __launch_bounds__(NTHR)
void k3_p_copy(const float* __restrict__ aq, const float* __restrict__ p,
               float* __restrict__ out,
               const float4* __restrict__ src4, float4* __restrict__ dst4,
               int C2, int n4) {
    const int blk = blockIdx.x, t = threadIdx.x;
    const int role = (blk >> 3) & 1;
    const int id   = ((blk >> 4) << 3) | (blk & 7);

    if (role) {  // copy
        #pragma unroll 4
        for (int i = C2 + id * NTHR + t; i < n4; i += 1024 * NTHR) dst4[i] = src4[i];
        return;
    }

    __shared__ float a_s[POOL * 8];
    const int l  = id & 7;
    const int bg = id >> 3;

    for (int i = t; i < POOL * 8; i += NTHR) {
        int bb = i & 7, k = i >> 3;
        a_s[i] = aq[(size_t)(bg * 8 + bb) * POOL + k];
    }
    __syncthreads();

    const float* pl = p + (size_t)l * POOL * CDIM + t;
    float acc[8][3];
    #pragma unroll
    for (int bb = 0; bb < 8; ++bb)
        #pragma unroll
        for (int j = 0; j < 3; ++j) acc[bb][j] = 0.f;

    for (int k = 0; k < POOL; ++k) {
        float p0 = pl[(size_t)k * CDIM];
        float p1 = pl[(size_t)k * CDIM + 256];
        float p2 = pl[(size_t)k * CDIM + 512];
        #pragma unroll
        for (int bb = 0; bb < 8; ++bb) {
            float a = a_s[k * 8 + bb];
            acc[bb][0] += a * p0;
            acc[bb][1] += a * p1;
            acc[bb][2] += a * p2;
        }
    }

    const size_t EK_SZ = (size_t)B_SZ * 4 * CDIM;
    #pragma unroll
    for (int bb = 0; bb < 8; ++bb) {
        int b = bg * 8 + bb;
        float* dst = (l < 4)
            ? out + (size_t)b * (4 * CDIM) + (size_t)l * CDIM
            : out + EK_SZ + (size_t)b * (4 * CDIM) + (size_t)(l - 4) * CDIM;
        dst[t]       = acc[bb][0];
        dst[t + 256] = acc[bb][1];
        dst[t + 512] = acc[bb][2];
    }
}

extern "C" void kernel_launch(void* const* d_in, const int* in_sizes, int n_in,
                              void* d_out, int out_size, void* d_ws, size_t ws_size,
                              hipStream_t stream) {
    const float* x_querry = (const float*)d_in[0];
    const float* x_block  = (const float*)d_in[1];
    const float* K        = (const float*)d_in[2];
    const float* A        = (const float*)d_in[3];
    const float* p        = (const float*)d_in[4];
    float* out = (float*)d_out;

    // workspace layout (floats)
    float* W1    = (float*)d_ws;                 // 100*768
    float* W2    = W1 + POOL * CDIM;             // 100*768
    float* knorm = W2 + POOL * CDIM;             // 100 (pad 128)
    float* aq    = knorm + 128;                  // 1024*100

    const size_t EK_SZ = (size_t)B_SZ * 4 * CDIM;
    const float4* src4 = (const float4*)x_block;
    float4* dst4 = (float4*)(out + 2 * EK_SZ);

    const int n4  = in_sizes[1] / 4;             // 38,731,776
    const int u   = n4 >> 4;
    const int C1  = u * 10;                      // ~62% during K1
    const int C2  = C1 + u * 3;                  // ~19% during K2, rest during K3

    k1_prep_copy<<<2048, NTHR, 0, stream>>>(A, K, W1, W2, knorm, src4, dst4, C1);
    k2_aq_copy  <<<2048, NTHR, 0, stream>>>(x_querry, W1, W2, knorm, aq, src4, dst4, C1, C2);
    k3_p_copy   <<<2048, NTHR, 0, stream>>>(aq, p, out, src4, dst4, C2, n4);
}